// Round 7
// baseline (166.109 us; speedup 1.0000x reference)
//
#include <hip/hip_runtime.h>

#define Bn 32
#define Cn 256
#define HWn 3136          // 56*56
#define HW4 784           // HWn/4
#define NPLANES 8192      // B*C
#define TOTAL_F4 6422528u // NPLANES * HW4
#define NTHREADS 256
#define NBLOCKS 2048
#define SWEEP (NBLOCKS * NTHREADS)   // 524288 f4 per iteration

typedef float f4 __attribute__((ext_vector_type(4)));

__device__ __forceinline__ float dot4(f4 a, f4 b) {
  return a.x * b.x + a.y * b.y + a.z * b.z + a.w * b.w;
}

#define NTLD(p) __builtin_nontemporal_load(p)

// ---------------------------------------------------------------------------
// K1: FLAT LINEAR SWEEP. 2048 blocks x 256 thr grid-stride the flat f4 index
// space, so at any instant the whole chip reads 3 contiguous ~2MB windows
// (x, cg, dg) -- DRAM row-buffer friendly, like the 6.3 TB/s copy kernel.
// (Previous wave-per-plane layout = ~7500 independent short streams -> row
// thrash -> 2.15 TB/s HBM.) Per-plane reduction: a 64-f4 wave window spans
// at most 2 planes (784 f4/plane), so do a segmented wave reduce and
// atomicAdd into plane accumulators (~13 atomics/plane total, negligible).
// Sums are UNSCALED; K2 folds in the 1/HW factor (pure positive scale ->
// identical ordering/masks).
// ---------------------------------------------------------------------------
__global__ __launch_bounds__(NTHREADS) void importance_flat(
    const float* __restrict__ x, const float* __restrict__ cg,
    const float* __restrict__ dg, float* __restrict__ cimsum,
    float* __restrict__ dimsum) {
  const int lane = threadIdx.x & 63;
  const f4* __restrict__ xp = (const f4*)x;
  const f4* __restrict__ cp = (const f4*)cg;
  const f4* __restrict__ dp = (const f4*)dg;

  unsigned n = blockIdx.x * NTHREADS + threadIdx.x;
#pragma unroll 2
  for (int k = 0; k < 13; ++k, n += SWEEP) {
    const bool valid = (n < TOTAL_F4);
    const unsigned nc = valid ? n : (TOTAL_F4 - 1);
    f4 xv = xp[nc];
    f4 cv = NTLD(cp + nc);
    f4 dv = NTLD(dp + nc);
    float dC = valid ? dot4(xv, cv) : 0.f;
    float dD = valid ? dot4(xv, dv) : 0.f;
    const unsigned p = nc / 784u;               // plane id
    const unsigned p0 = __shfl(p, 0);
    const unsigned p63 = __shfl(p, 63);

    // segment 0 (plane p0)
    float c0 = (p == p0) ? dC : 0.f;
    float d0 = (p == p0) ? dD : 0.f;
    for (int off = 32; off; off >>= 1) {
      c0 += __shfl_down(c0, off);
      d0 += __shfl_down(d0, off);
    }
    // segment 1 (plane p63) -- wave-uniform branch, taken ~1/12 of windows
    if (p63 != p0) {
      float c1 = (p == p63) ? dC : 0.f;
      float d1 = (p == p63) ? dD : 0.f;
      for (int off = 32; off; off >>= 1) {
        c1 += __shfl_down(c1, off);
        d1 += __shfl_down(d1, off);
      }
      if (lane == 0) {
        atomicAdd(&cimsum[p63], c1);
        atomicAdd(&dimsum[p63], d1);
      }
    }
    if (lane == 0) {
      atomicAdd(&cimsum[p0], c0);
      atomicAdd(&dimsum[p0], d0);
    }
  }
}

// ---------------------------------------------------------------------------
// K2: per-sample quantile thresholds (rank selection over 256 channels) and
// mask generation. Inputs are UNSCALED plane sums; multiply by 1/HW here.
// quantile(0.5): pos = 127.5 -> 0.5*(s127+s128); quantile(0.8): pos=204 -> s204
// ---------------------------------------------------------------------------
__global__ __launch_bounds__(NTHREADS) void quantile_mask_kernel(
    const float* __restrict__ cim, const float* __restrict__ dimv,
    float* __restrict__ m1, float* __restrict__ m2, float* __restrict__ mdi) {
  const int b = blockIdx.x;
  const int c = threadIdx.x;
  __shared__ float sc[Cn], sd[Cn];
  __shared__ float q127, q128, q204;
  const float v = cim[b * Cn + c] * (1.0f / HWn);
  const float w = dimv[b * Cn + c] * (1.0f / HWn);
  sc[c] = v;
  sd[c] = w;
  __syncthreads();

  int cl = 0, ce = 0, dl = 0, de = 0;
  for (int j = 0; j < Cn; ++j) {
    float u = sc[j];
    cl += (u < v);
    ce += (u == v);
    float t = sd[j];
    dl += (t < w);
    de += (t == w);
  }
  if (cl <= 127 && 127 < cl + ce) q127 = v;
  if (cl <= 128 && 128 < cl + ce) q128 = v;
  if (dl <= 204 && 204 < dl + de) q204 = w;
  __syncthreads();

  const float cthr = 0.5f * (q127 + q128);
  const float dthr = q204;
  const bool cs = v > cthr;
  const bool ds = w > dthr;
  m1[b * Cn + c] = (cs && ds) ? 1.f : 0.f;
  m2[b * Cn + c] = (!cs && ds) ? 1.f : 0.f;
  mdi[b * Cn + c] = ds ? 0.f : 1.f;
}

// ---------------------------------------------------------------------------
// K3: out[b,c,:] = A*x[b,c,:] + B1*x[sb,c,:] + B2*x[db,c,:]
// x reads come mostly from L3; out never read back -> nontemporal stores.
// Already at the 103MB-write floor (~15 us).
// ---------------------------------------------------------------------------
__global__ __launch_bounds__(NTHREADS) void mix_kernel(
    const float* __restrict__ x, const float* __restrict__ ms,
    const int* __restrict__ same_idx, const int* __restrict__ diff_idx,
    const float* __restrict__ m1, const float* __restrict__ m2,
    const float* __restrict__ mdi, float* __restrict__ out) {
  const int bc = blockIdx.x;
  const int b = bc >> 8;
  const int c = bc & 255;
  const int sb = same_idx[b];
  const int db = diff_idx[b];
  const float s0 = ms[b * 2 + 0];
  const float s1 = ms[b * 2 + 1];

  const float A = mdi[bc] + s0 * m1[bc] + s1 * m2[bc];
  const float B1 = (1.f - s0) * m1[sb * Cn + c];
  const float B2 = (1.f - s1) * m2[db * Cn + c];

  const f4* __restrict__ xp = (const f4*)(x + (size_t)bc * HWn);
  const f4* __restrict__ xs = (const f4*)(x + ((size_t)sb * Cn + c) * HWn);
  const f4* __restrict__ xd = (const f4*)(x + ((size_t)db * Cn + c) * HWn);
  f4* __restrict__ op = (f4*)(out + (size_t)bc * HWn);

  const bool u1 = (B1 != 0.f);
  const bool u2 = (B2 != 0.f);
  const int t = threadIdx.x;

  f4 r0, r1, r2;
  {
    f4 xv0 = xp[t];
    f4 xv1 = xp[t + 256];
    f4 xv2 = xp[t + 512];
    r0 = A * xv0;
    r1 = A * xv1;
    r2 = A * xv2;
  }
  if (u1) {
    f4 s0v = xs[t];
    f4 s1v = xs[t + 256];
    f4 s2v = xs[t + 512];
    r0 += B1 * s0v;
    r1 += B1 * s1v;
    r2 += B1 * s2v;
  }
  if (u2) {
    f4 d0v = xd[t];
    f4 d1v = xd[t + 256];
    f4 d2v = xd[t + 512];
    r0 += B2 * d0v;
    r1 += B2 * d1v;
    r2 += B2 * d2v;
  }
  __builtin_nontemporal_store(r0, op + t);
  __builtin_nontemporal_store(r1, op + t + 256);
  __builtin_nontemporal_store(r2, op + t + 512);

  if (t < 16) {
    f4 xv3 = xp[768 + t];
    f4 r3 = A * xv3;
    if (u1) {
      f4 s3v = xs[768 + t];
      r3 += B1 * s3v;
    }
    if (u2) {
      f4 d3v = xd[768 + t];
      r3 += B2 * d3v;
    }
    __builtin_nontemporal_store(r3, op + 768 + t);
  }
}

extern "C" void kernel_launch(void* const* d_in, const int* in_sizes, int n_in,
                              void* d_out, int out_size, void* d_ws, size_t ws_size,
                              hipStream_t stream) {
  const float* x  = (const float*)d_in[0];
  const float* cg = (const float*)d_in[1];
  const float* dg = (const float*)d_in[2];
  const float* ms = (const float*)d_in[3];
  // d_in[4] = y, d_in[5] = domain (unused: index pickers precomputed)
  const int* same_idx = (const int*)d_in[6];
  const int* diff_idx = (const int*)d_in[7];
  float* out = (float*)d_out;

  float* ws = (float*)d_ws;
  float* cim  = ws;                // B*C  (unscaled sums, atomically accumulated)
  float* dimv = ws + Bn * Cn;      // B*C
  float* m1   = ws + 2 * Bn * Cn;  // B*C
  float* m2   = ws + 3 * Bn * Cn;  // B*C
  float* mdi  = ws + 4 * Bn * Cn;  // B*C

  // zero the atomic accumulators (graph-capturable async memset)
  hipMemsetAsync(cim, 0, 2 * Bn * Cn * sizeof(float), stream);

  importance_flat<<<NBLOCKS, NTHREADS, 0, stream>>>(x, cg, dg, cim, dimv);
  quantile_mask_kernel<<<Bn, NTHREADS, 0, stream>>>(cim, dimv, m1, m2, mdi);
  mix_kernel<<<Bn * Cn, NTHREADS, 0, stream>>>(x, ms, same_idx, diff_idx, m1, m2, mdi, out);
}

// Round 8
// 88.789 us; speedup vs baseline: 1.8708x; 1.8708x over previous
//
#include <hip/hip_runtime.h>

#define Bn 32
#define Cn 256
#define HWn 3136          // 56*56
#define HW4 784           // HWn/4 = 64*12 + 16
#define NTHREADS 256

typedef float f4 __attribute__((ext_vector_type(4)));

__device__ __forceinline__ float dot4(f4 a, f4 b) {
  return a.x * b.x + a.y * b.y + a.z * b.z + a.w * b.w;
}

#define SB() __builtin_amdgcn_sched_barrier(0)

// ---------------------------------------------------------------------------
// K1: one wave per (b,c) plane; 2048 blocks x 256 thr = 8192 waves.
// R6 structure (sched_barrier-pinned 3-stage pipeline, VGPR=60) with ONE
// change: NO nontemporal hints on any load. A/B test: R3/R4/R6 all plateaued
// at 2.15 TB/s HBM with NT loads on cg/dg; if nt demotes L2 allocation the
// two HBM-destined streams pay full latency per request. Plain loads restore
// normal L2 line allocation/MSHR merging.
// ---------------------------------------------------------------------------
__global__ __launch_bounds__(NTHREADS, 2) void importance_kernel(
    const float* __restrict__ x, const float* __restrict__ cg,
    const float* __restrict__ dg, float* __restrict__ cim,
    float* __restrict__ dimv) {
  const int lane = threadIdx.x & 63;
  const int bc = (blockIdx.x << 2) | (threadIdx.x >> 6);  // plane id 0..8191
  const size_t base = (size_t)bc * HWn;
  const f4* __restrict__ xp = (const f4*)(x + base);
  const f4* __restrict__ cp = (const f4*)(cg + base);
  const f4* __restrict__ dp = (const f4*)(dg + base);

  // ---- region 1: issue tail + stage0 + stage1 loads (27 f4 per thread) ----
  f4 xt = {0.f, 0.f, 0.f, 0.f}, ct = xt, dt = xt;
  if (lane < 16) {
    xt = xp[768 + lane];
    ct = cp[768 + lane];
    dt = dp[768 + lane];
  }
  f4 xa0 = xp[lane +   0], xa1 = xp[lane +  64], xa2 = xp[lane + 128], xa3 = xp[lane + 192];
  f4 ca0 = cp[lane +   0], ca1 = cp[lane +  64], ca2 = cp[lane + 128], ca3 = cp[lane + 192];
  f4 da0 = dp[lane +   0], da1 = dp[lane +  64], da2 = dp[lane + 128], da3 = dp[lane + 192];

  f4 xb0 = xp[lane + 256], xb1 = xp[lane + 320], xb2 = xp[lane + 384], xb3 = xp[lane + 448];
  f4 cb0 = cp[lane + 256], cb1 = cp[lane + 320], cb2 = cp[lane + 384], cb3 = cp[lane + 448];
  f4 db0 = dp[lane + 256], db1 = dp[lane + 320], db2 = dp[lane + 384], db3 = dp[lane + 448];
  SB();

  // ---- region 2: consume stage0, issue stage2 loads (12 f4) ----
  float accC = dot4(xa0, ca0) + dot4(xa1, ca1) + dot4(xa2, ca2) + dot4(xa3, ca3);
  float accD = dot4(xa0, da0) + dot4(xa1, da1) + dot4(xa2, da2) + dot4(xa3, da3);
  f4 xc0 = xp[lane + 512], xc1 = xp[lane + 576], xc2 = xp[lane + 640], xc3 = xp[lane + 704];
  f4 cc0 = cp[lane + 512], cc1 = cp[lane + 576], cc2 = cp[lane + 640], cc3 = cp[lane + 704];
  f4 dc0 = dp[lane + 512], dc1 = dp[lane + 576], dc2 = dp[lane + 640], dc3 = dp[lane + 704];
  SB();

  // ---- region 3: consume stage1 ----
  accC += dot4(xb0, cb0) + dot4(xb1, cb1) + dot4(xb2, cb2) + dot4(xb3, cb3);
  accD += dot4(xb0, db0) + dot4(xb1, db1) + dot4(xb2, db2) + dot4(xb3, db3);
  SB();

  // ---- region 4: consume stage2 + tail ----
  accC += dot4(xc0, cc0) + dot4(xc1, cc1) + dot4(xc2, cc2) + dot4(xc3, cc3);
  accD += dot4(xc0, dc0) + dot4(xc1, dc1) + dot4(xc2, dc2) + dot4(xc3, dc3);
  accC += dot4(xt, ct);
  accD += dot4(xt, dt);

  // wave-local reduce (64 lanes)
  for (int off = 32; off; off >>= 1) {
    accC += __shfl_down(accC, off);
    accD += __shfl_down(accD, off);
  }
  if (lane == 0) {
    cim[bc] = accC * (1.0f / HWn);
    dimv[bc] = accD * (1.0f / HWn);
  }
}

// ---------------------------------------------------------------------------
// K2: per-sample quantile thresholds (rank selection over 256 channels) and
// mask generation: m1 = cs&ds, m2 = (!cs)&ds, mdi = !ds
// quantile(0.5): pos = 127.5 -> 0.5*(s127+s128); quantile(0.8): pos=204 -> s204
// ---------------------------------------------------------------------------
__global__ __launch_bounds__(NTHREADS) void quantile_mask_kernel(
    const float* __restrict__ cim, const float* __restrict__ dimv,
    float* __restrict__ m1, float* __restrict__ m2, float* __restrict__ mdi) {
  const int b = blockIdx.x;
  const int c = threadIdx.x;
  __shared__ float sc[Cn], sd[Cn];
  __shared__ float q127, q128, q204;
  const float v = cim[b * Cn + c];
  const float w = dimv[b * Cn + c];
  sc[c] = v;
  sd[c] = w;
  __syncthreads();

  int cl = 0, ce = 0, dl = 0, de = 0;
  for (int j = 0; j < Cn; ++j) {
    float u = sc[j];
    cl += (u < v);
    ce += (u == v);
    float t = sd[j];
    dl += (t < w);
    de += (t == w);
  }
  if (cl <= 127 && 127 < cl + ce) q127 = v;
  if (cl <= 128 && 128 < cl + ce) q128 = v;
  if (dl <= 204 && 204 < dl + de) q204 = w;
  __syncthreads();

  const float cthr = 0.5f * (q127 + q128);
  const float dthr = q204;
  const bool cs = v > cthr;
  const bool ds = w > dthr;
  m1[b * Cn + c] = (cs && ds) ? 1.f : 0.f;
  m2[b * Cn + c] = (!cs && ds) ? 1.f : 0.f;
  mdi[b * Cn + c] = ds ? 0.f : 1.f;
}

// ---------------------------------------------------------------------------
// K3: out[b,c,:] = A*x[b,c,:] + B1*x[sb,c,:] + B2*x[db,c,:]
// x reads come mostly from L3; out never read back -> nontemporal stores.
// ---------------------------------------------------------------------------
__global__ __launch_bounds__(NTHREADS) void mix_kernel(
    const float* __restrict__ x, const float* __restrict__ ms,
    const int* __restrict__ same_idx, const int* __restrict__ diff_idx,
    const float* __restrict__ m1, const float* __restrict__ m2,
    const float* __restrict__ mdi, float* __restrict__ out) {
  const int bc = blockIdx.x;
  const int b = bc >> 8;
  const int c = bc & 255;
  const int sb = same_idx[b];
  const int db = diff_idx[b];
  const float s0 = ms[b * 2 + 0];
  const float s1 = ms[b * 2 + 1];

  const float A = mdi[bc] + s0 * m1[bc] + s1 * m2[bc];
  const float B1 = (1.f - s0) * m1[sb * Cn + c];
  const float B2 = (1.f - s1) * m2[db * Cn + c];

  const f4* __restrict__ xp = (const f4*)(x + (size_t)bc * HWn);
  const f4* __restrict__ xs = (const f4*)(x + ((size_t)sb * Cn + c) * HWn);
  const f4* __restrict__ xd = (const f4*)(x + ((size_t)db * Cn + c) * HWn);
  f4* __restrict__ op = (f4*)(out + (size_t)bc * HWn);

  const bool u1 = (B1 != 0.f);
  const bool u2 = (B2 != 0.f);
  const int t = threadIdx.x;

  f4 r0, r1, r2;
  {
    f4 xv0 = xp[t];
    f4 xv1 = xp[t + 256];
    f4 xv2 = xp[t + 512];
    r0 = A * xv0;
    r1 = A * xv1;
    r2 = A * xv2;
  }
  if (u1) {
    f4 s0v = xs[t];
    f4 s1v = xs[t + 256];
    f4 s2v = xs[t + 512];
    r0 += B1 * s0v;
    r1 += B1 * s1v;
    r2 += B1 * s2v;
  }
  if (u2) {
    f4 d0v = xd[t];
    f4 d1v = xd[t + 256];
    f4 d2v = xd[t + 512];
    r0 += B2 * d0v;
    r1 += B2 * d1v;
    r2 += B2 * d2v;
  }
  __builtin_nontemporal_store(r0, op + t);
  __builtin_nontemporal_store(r1, op + t + 256);
  __builtin_nontemporal_store(r2, op + t + 512);

  if (t < 16) {
    f4 xv3 = xp[768 + t];
    f4 r3 = A * xv3;
    if (u1) {
      f4 s3v = xs[768 + t];
      r3 += B1 * s3v;
    }
    if (u2) {
      f4 d3v = xd[768 + t];
      r3 += B2 * d3v;
    }
    __builtin_nontemporal_store(r3, op + 768 + t);
  }
}

extern "C" void kernel_launch(void* const* d_in, const int* in_sizes, int n_in,
                              void* d_out, int out_size, void* d_ws, size_t ws_size,
                              hipStream_t stream) {
  const float* x  = (const float*)d_in[0];
  const float* cg = (const float*)d_in[1];
  const float* dg = (const float*)d_in[2];
  const float* ms = (const float*)d_in[3];
  // d_in[4] = y, d_in[5] = domain (unused: index pickers precomputed)
  const int* same_idx = (const int*)d_in[6];
  const int* diff_idx = (const int*)d_in[7];
  float* out = (float*)d_out;

  float* ws = (float*)d_ws;
  float* cim  = ws;                // B*C
  float* dimv = ws + Bn * Cn;      // B*C
  float* m1   = ws + 2 * Bn * Cn;  // B*C
  float* m2   = ws + 3 * Bn * Cn;  // B*C
  float* mdi  = ws + 4 * Bn * Cn;  // B*C

  importance_kernel<<<(Bn * Cn) / 4, NTHREADS, 0, stream>>>(x, cg, dg, cim, dimv);
  quantile_mask_kernel<<<Bn, NTHREADS, 0, stream>>>(cim, dimv, m1, m2, mdi);
  mix_kernel<<<Bn * Cn, NTHREADS, 0, stream>>>(x, ms, same_idx, diff_idx, m1, m2, mdi, out);
}